// Round 15
// baseline (829.258 us; speedup 1.0000x reference)
//
#include <hip/hip_runtime.h>
#include <hip/hip_bf16.h>

#define DD 128
#define EPSN 1e-12f
#define JSPLIT 8

typedef __attribute__((ext_vector_type(8))) short bf16x8;
typedef __attribute__((ext_vector_type(16))) float f32x16;

__device__ __forceinline__ unsigned short f2b(float f) {
  unsigned int u = __builtin_bit_cast(unsigned int, f);
  return (unsigned short)((u + 0x7fffu + ((u >> 16) & 1u)) >> 16);
}
__device__ __forceinline__ float b2f(unsigned short u) {
  unsigned int v = ((unsigned int)u) << 16;
  return __builtin_bit_cast(float, v);
}

// ---------------------------------------------------------------------------
// T-partials for BOTH tensors, atomic-free (R13-exact, proven).
// grid(2,2,128) x 256.
// ---------------------------------------------------------------------------
__global__ __launch_bounds__(256) void k_ata_part(
    const float* __restrict__ f1, const float* __restrict__ f2,
    float* __restrict__ Tpart,
    unsigned short* __restrict__ b1, unsigned short* __restrict__ b2,
    int chunkRows) {
  __shared__ float si[128][64];
  __shared__ float sj[128][64];
  const int sel = blockIdx.z >> 6;
  const int zc = blockIdx.z & 63;
  const float* X = sel ? f2 : f1;
  unsigned short* Xb16 = sel ? b2 : b1;
  const int bi = blockIdx.x, bj = blockIdx.y;
  const int n0 = zc * chunkRows;
  const int t = threadIdx.x;
  const bool emit = (bi == 0) && (bj == 1);
  for (int idx = t; idx < 128 * 16; idx += 256) {
    int r = idx >> 4, c4 = idx & 15;
    float4 a = *((const float4*)(X + (size_t)(n0 + r) * DD + bi * 64) + c4);
    float4 b = *((const float4*)(X + (size_t)(n0 + r) * DD + bj * 64) + c4);
    *(float4*)&si[r][c4 * 4] = a;
    *(float4*)&sj[r][c4 * 4] = b;
    if (emit) {
      ushort4 oa, ob;
      oa.x = f2b(a.x); oa.y = f2b(a.y); oa.z = f2b(a.z); oa.w = f2b(a.w);
      ob.x = f2b(b.x); ob.y = f2b(b.y); ob.z = f2b(b.z); ob.w = f2b(b.w);
      *(ushort4*)&Xb16[(size_t)(n0 + r) * DD + c4 * 4] = oa;
      *(ushort4*)&Xb16[(size_t)(n0 + r) * DD + 64 + c4 * 4] = ob;
    }
  }
  __syncthreads();
  const int tx = t & 15, ty = t >> 4;
  float acc[4][4] = {};
  for (int n = 0; n < 128; ++n) {
    float4 av = *(const float4*)&si[n][ty * 4];
    float4 bv = *(const float4*)&sj[n][tx * 4];
    float a[4] = {av.x, av.y, av.z, av.w};
    float b[4] = {bv.x, bv.y, bv.z, bv.w};
#pragma unroll
    for (int i = 0; i < 4; ++i)
#pragma unroll
      for (int j = 0; j < 4; ++j) acc[i][j] += a[i] * b[j];
  }
  float* tp = Tpart + (size_t)(sel * 64 + zc) * (DD * DD);
#pragma unroll
  for (int i = 0; i < 4; ++i) {
    float4 v = make_float4(acc[i][0], acc[i][1], acc[i][2], acc[i][3]);
    *(float4*)&tp[(size_t)(bi * 64 + ty * 4 + i) * DD + bj * 64 + tx * 4] = v;
  }
}

// ---------------------------------------------------------------------------
// Reduce 64 T-partial slices -> T (both tensors).  grid(16, 2) x 256.
// ---------------------------------------------------------------------------
__global__ __launch_bounds__(256) void k_tred(const float* __restrict__ Tpart,
                                              float* __restrict__ T1,
                                              float* __restrict__ T2) {
  const int sel = blockIdx.y;
  const int e0 = (blockIdx.x * 256 + threadIdx.x) * 4;
  const float* base = Tpart + (size_t)sel * 64 * (DD * DD);
  float4 s = make_float4(0.f, 0.f, 0.f, 0.f);
#pragma unroll
  for (int z = 0; z < 64; ++z) {
    float4 v = *(const float4*)(base + (size_t)z * (DD * DD) + e0);
    s.x += v.x; s.y += v.y; s.z += v.z; s.w += v.w;
  }
  float* T = sel ? T2 : T1;
  *(float4*)&T[e0] = s;
}

// ---------------------------------------------------------------------------
// MFMA fused attention — R13 inner loop byte-identical, but blocks split to
// 256 threads / 64 i-rows (wb moved half into grid): 4 independent blocks/CU
// (40KB LDS) instead of 2 lockstepped 512-thr blocks -> cross-block pipe
// overlap.  grid(N/64, JSPLIT) x 256.
// ---------------------------------------------------------------------------
__global__ __launch_bounds__(256, 4) void k_attn(
    const unsigned short* __restrict__ Xb, const unsigned short* __restrict__ Yb,
    unsigned short* __restrict__ Hps, unsigned short* __restrict__ Hx,
    float* __restrict__ rbp, int N) {
  __shared__ __align__(16) char LP[40960];
  unsigned short* Yst = (unsigned short*)LP;   // [2][10240] tr-subtiles (40KB)
  unsigned short* mrgb = (unsigned short*)LP;  // epilogue [64][128] bf16 16KB
  float* rs = (float*)(LP + 16384);            // epilogue [2][32] rowabs merge
  const int t = threadIdx.x;
  const int w = t >> 6, l = t & 63, lh = l >> 5, ln = l & 31;
  const int wb = w >> 1, jh = w & 1;  // wb in 0..1 (64 i-rows/block)
  const int i0 = blockIdx.x * 64;
  const size_t ND = (size_t)N * DD;
  const int jbase = blockIdx.y * (N / JSPLIT);
  const int jiters = (N / JSPLIT) / 64;

  // X fragments in registers (loop-invariant)
  const int xrow = i0 + wb * 32 + ln;
  bf16x8 xf[8];
#pragma unroll
  for (int kc = 0; kc < 8; ++kc)
    xf[kc] = *(const bf16x8*)(Xb + (size_t)xrow * DD + kc * 16 + lh * 8);

  f32x16 acc2[4];
#pragma unroll
  for (int cb = 0; cb < 4; ++cb)
#pragma unroll
    for (int r = 0; r < 16; ++r) acc2[cb][r] = 0.f;
  float rsum = 0.f;

  // staging: 256 threads x 4 chunks; thread t -> row sjj, chunks ch0+4c
  const int sjj = t >> 2;
  const int ch0 = t & 3;
  const int SB = sjj >> 2;
  bf16x8 rg[4];
  {
    const unsigned short* yb = Yb + (size_t)(jbase + sjj) * DD + ch0 * 8;
#pragma unroll
    for (int c = 0; c < 4; ++c) rg[c] = *(const bf16x8*)(yb + 32 * c);
  }
#pragma unroll
  for (int c = 0; c < 4; ++c) {
    int ch = ch0 + 4 * c;
    int blk = SB * 8 + ((ch >> 1) ^ (SB & 7));
    int eoff = 80 * blk + (sjj & 3) * 16 + (((ch & 1) ^ (SB & 1)) << 3);
    *(bf16x8*)&Yst[eoff] = rg[c];
  }

  const unsigned ystBase0 = (unsigned)(size_t)Yst;
  const int d4b = ln >> 4;
  const int xrb = (ln & 15) << 1;
  const int yr = jh * 32 + ln;
  const int YB = yr >> 2;

  for (int jt = 0; jt < jiters; ++jt) {
    const int cur = jt & 1;
    __syncthreads();  // buf[cur] writes visible; prev readers done
    // ---- EARLY: issue ph2 B tr-reads (depend only on staged tile)
    const unsigned yB = ystBase0 + (unsigned)(cur * 20480);
    uint2 tvv[2][4][2];
#pragma unroll
    for (int f = 0; f < 2; ++f)
#pragma unroll
      for (int h2 = 0; h2 < 2; ++h2) {
        const int B = jh * 8 + f * 4 + lh * 2 + h2;
        const int b7 = B & 7;
        const unsigned xr2 = (unsigned)(xrb ^ (h2 << 4));
#pragma unroll
        for (int cb = 0; cb < 4; ++cb) {
          int blk = B * 8 + ((cb * 2 + d4b) ^ b7);
          unsigned a = yB + (unsigned)(blk * 160) + xr2;
          asm volatile("ds_read_b64_tr_b16 %0, %1"
                       : "=v"(tvv[f][cb][h2])
                       : "v"(a));
        }
      }
    // T14: prefetch next Y tile into regs
    if (jt + 1 < jiters) {
      const unsigned short* yb =
          Yb + (size_t)(jbase + (jt + 1) * 64 + sjj) * DD + ch0 * 8;
#pragma unroll
      for (int c = 0; c < 4; ++c) rg[c] = *(const bf16x8*)(yb + 32 * c);
    }
    // ---- ph1 (swapped): lane ln holds S-row i; two MFMA chains
    f32x16 s0, s1;
#pragma unroll
    for (int r = 0; r < 16; ++r) { s0[r] = 0.f; s1[r] = 0.f; }
#pragma unroll
    for (int kc = 0; kc < 8; ++kc) {
      int ck = kc * 2 + lh;
      int off = 80 * (YB * 8 + ((ck >> 1) ^ (YB & 7))) + (yr & 3) * 16 +
                (((ck & 1) ^ (YB & 1)) << 3);
      bf16x8 yv = *(const bf16x8*)&Yst[cur * 10240 + off];
      if (kc & 1)
        s1 = __builtin_amdgcn_mfma_f32_32x32x16_bf16(yv, xf[kc], s1, 0, 0, 0);
      else
        s0 = __builtin_amdgcn_mfma_f32_32x32x16_bf16(yv, xf[kc], s0, 0, 0, 0);
    }
    f32x16 s;
#pragma unroll
    for (int r = 0; r < 16; ++r) s[r] = s0[r] + s1[r];
    // ---- diag zero (tile-on-diagonal only)
    const int j0g = jbase + jt * 64 + jh * 32;
    if (i0 + wb * 32 == j0g) {
#pragma unroll
      for (int r = 0; r < 16; ++r) {
        int jl = (r & 3) + 8 * (r >> 2) + 4 * lh;
        if (jl == ln) s[r] = 0.f;
      }
    }
    // ---- rowabs (lane-local row)
#pragma unroll
    for (int r = 0; r < 16; ++r) rsum += fabsf(s[r]);
    // ---- pack S row to bf16 fragments (cvt_pk + permlane32_swap)
    unsigned pq[8];
#pragma unroll
    for (int q = 0; q < 8; ++q)
      asm("v_cvt_pk_bf16_f32 %0, %1, %2"
          : "=v"(pq[q])
          : "v"(s[2 * q]), "v"(s[2 * q + 1]));
    bf16x8 av2[2];
#pragma unroll
    for (int f = 0; f < 2; ++f) {
      unsigned a0 = pq[4 * f + 0], b0 = pq[4 * f + 2];
      unsigned a1 = pq[4 * f + 1], b1 = pq[4 * f + 3];
      asm volatile("v_permlane32_swap_b32 %0, %1" : "+v"(a0), "+v"(b0));
      asm volatile("v_permlane32_swap_b32 %0, %1" : "+v"(a1), "+v"(b1));
      av2[f] = __builtin_bit_cast(bf16x8, make_uint4(a0, a1, b0, b1));
    }
    // ---- drain tr reads, fence, ph2 MFMAs (rule #18)
    asm volatile("s_waitcnt lgkmcnt(0)" ::: "memory");
    __builtin_amdgcn_sched_barrier(0);
#pragma unroll
    for (int f = 0; f < 2; ++f)
#pragma unroll
      for (int cb = 0; cb < 4; ++cb) {
        bf16x8 bv = __builtin_bit_cast(
            bf16x8, make_uint4(tvv[f][cb][0].x, tvv[f][cb][0].y,
                               tvv[f][cb][1].x, tvv[f][cb][1].y));
        acc2[cb] =
            __builtin_amdgcn_mfma_f32_32x32x16_bf16(av2[f], bv, acc2[cb], 0, 0, 0);
      }
    // ---- write prefetched regs -> buf[cur^1]
    if (jt + 1 < jiters) {
      int bo = (cur ^ 1) * 10240;
#pragma unroll
      for (int c = 0; c < 4; ++c) {
        int ch = ch0 + 4 * c;
        int blk = SB * 8 + ((ch >> 1) ^ (SB & 7));
        int eoff = bo + 80 * blk + (sjj & 3) * 16 + (((ch & 1) ^ (SB & 1)) << 3);
        *(bf16x8*)&Yst[eoff] = rg[c];
      }
    }
  }
  // ---- epilogue: merge j-halves in LDS (bf16, aliases dead Yst)
  rsum += __shfl_xor(rsum, 32);
  __syncthreads();
  if (jh == 1) {
#pragma unroll
    for (int cb = 0; cb < 4; ++cb)
#pragma unroll
      for (int r = 0; r < 16; ++r) {
        int rl = (r & 3) + 8 * (r >> 2) + 4 * lh;
        mrgb[(wb * 32 + rl) * 128 + cb * 32 + ln] = f2b(acc2[cb][r]);
      }
    if (l < 32) rs[wb * 32 + ln] = rsum;
  }
  __syncthreads();
  if (jh == 0) {
    unsigned short* hp;
    int rstr;
    if (blockIdx.y < 6) {
      hp = Hps + (size_t)blockIdx.y * ND;
      rstr = 128;
    } else {
      hp = Hx + (blockIdx.y - 6) * 128;
      rstr = 256;
    }
#pragma unroll
    for (int cb = 0; cb < 4; ++cb)
#pragma unroll
      for (int r = 0; r < 16; ++r) {
        int rl = (r & 3) + 8 * (r >> 2) + 4 * lh;
        float v = acc2[cb][r] + b2f(mrgb[(wb * 32 + rl) * 128 + cb * 32 + ln]);
        hp[(size_t)(i0 + wb * 32 + rl) * rstr + cb * 32 + ln] = f2b(v);
      }
    if (l < 32)
      rbp[(size_t)blockIdx.y * N + i0 + wb * 32 + ln] = rsum + rs[wb * 32 + ln];
  }
}

// ---------------------------------------------------------------------------
// Fused post-attention chain, 64 rows/block (R12/R13-exact, proven).
// ---------------------------------------------------------------------------
__device__ __forceinline__ void stageWf(const float* __restrict__ g,
                                        unsigned short (*L)[128], int t) {
#pragma unroll
  for (int idx = t; idx < 2048; idx += 512) {
    int r = idx >> 4, ch = idx & 15;
    const float* p = g + r * 128 + ch * 8;
    float4 u = *(const float4*)p, v = *(const float4*)(p + 4);
    bf16x8 o;
    o[0] = (short)f2b(u.x); o[1] = (short)f2b(u.y);
    o[2] = (short)f2b(u.z); o[3] = (short)f2b(u.w);
    o[4] = (short)f2b(v.x); o[5] = (short)f2b(v.y);
    o[6] = (short)f2b(v.z); o[7] = (short)f2b(v.w);
    *(bf16x8*)&L[r][(ch ^ (r & 15)) << 3] = o;
  }
}
__device__ __forceinline__ bf16x8 wfrag(const unsigned short (*L)[128], int row,
                                        int kc, int lh) {
  int ch = kc * 2 + lh;
  return *(const bf16x8*)&L[row][(ch ^ (row & 15)) << 3];
}

__global__ __launch_bounds__(512) void k_post(
    const unsigned short* __restrict__ Hps, const unsigned short* __restrict__ Hx,
    const float* __restrict__ rbp, const unsigned short* __restrict__ fselfb,
    const unsigned short* __restrict__ fbaseb,
    const float* __restrict__ Tf,
    const float* __restrict__ Wmf, const float* __restrict__ bm,
    const float* __restrict__ Wsf, const float* __restrict__ bs,
    const float* __restrict__ Wg1f, const float* __restrict__ bg1,
    const float* __restrict__ Wg2f, const float* __restrict__ bg2,
    float* __restrict__ outNorm, float* __restrict__ outValF,
    unsigned short* __restrict__ outValB, int N) {
  __shared__ unsigned short WL[128][128];
  __shared__ __align__(16) char pool[64 * 132 * 4];
  __shared__ float blds[3][128];
  __shared__ float rowpart[8][32];
  unsigned short(*Mb)[128] = (unsigned short(*)[128])pool;
  unsigned short(*Sb)[128] = (unsigned short(*)[128])(pool + 16384);
  float(*tr)[132] = (float(*)[132])pool;
  float(*hs)[132] = (float(*)[132])pool;

  const int t = threadIdx.x;
  const int w = t >> 6, l = t & 63, ln = l & 31, lh = l >> 5;
  const int grp = w >> 2, cq = w & 3;
  const int i0 = blockIdx.x * 64;
  const int lrow = grp * 32 + ln;
  const int row = i0 + lrow;
  const size_t ND = (size_t)N * DD;

  for (int idx = t; idx < 1024; idx += 512) {
    int r = idx >> 4, c8 = idx & 15;
    float a8[8] = {0.f, 0.f, 0.f, 0.f, 0.f, 0.f, 0.f, 0.f};
#pragma unroll
    for (int sp = 0; sp < 8; ++sp) {
      const unsigned short* p =
          (sp < 6) ? Hps + (size_t)sp * ND + (size_t)(i0 + r) * DD + c8 * 8
                   : Hx + (size_t)(i0 + r) * 256 + (sp - 6) * 128 + c8 * 8;
      bf16x8 v = *(const bf16x8*)p;
#pragma unroll
      for (int e = 0; e < 8; ++e) a8[e] += b2f((unsigned short)v[e]);
    }
    *(float4*)&hs[r][c8 * 8] = make_float4(a8[0], a8[1], a8[2], a8[3]);
    *(float4*)&hs[r][c8 * 8 + 4] = make_float4(a8[4], a8[5], a8[6], a8[7]);
  }
  if (t < 128) {
    blds[0][t] = bm[t];
    blds[1][t] = bs[t];
    blds[2][t] = bg1[t] + bg2[t];
  }
  stageWf(Tf, WL, t);
  __syncthreads();

  float rbv = 0.f;
#pragma unroll
  for (int sp = 0; sp < 8; ++sp) rbv += rbp[(size_t)sp * N + row];
  const float sc = (1.f / (float)N) / fmaxf(rbv, EPSN);
  bf16x8 bfA[8], bfS[8], bfB[8];
#pragma unroll
  for (int kc = 0; kc < 8; ++kc) {
    const float* hp = &hs[lrow][kc * 16 + lh * 8];
    float4 u = *(const float4*)hp;
    float4 v = *(const float4*)(hp + 4);
    bf16x8 a;
    a[0] = (short)f2b(u.x * sc); a[1] = (short)f2b(u.y * sc);
    a[2] = (short)f2b(u.z * sc); a[3] = (short)f2b(u.w * sc);
    a[4] = (short)f2b(v.x * sc); a[5] = (short)f2b(v.y * sc);
    a[6] = (short)f2b(v.z * sc); a[7] = (short)f2b(v.w * sc);
    bfA[kc] = a;
    bfS[kc] = *(const bf16x8*)(fselfb + (size_t)row * DD + kc * 16 + lh * 8);
    bfB[kc] = *(const bf16x8*)(fbaseb + (size_t)row * DD + kc * 16 + lh * 8);
  }

  f32x16 acc;
#pragma unroll
  for (int r = 0; r < 16; ++r) acc[r] = 0.f;
#pragma unroll
  for (int kc = 0; kc < 8; ++kc)
    acc = __builtin_amdgcn_mfma_f32_32x32x16_bf16(
        wfrag(WL, cq * 32 + ln, kc, lh), bfB[kc], acc, 0, 0, 0);
  float sab = 0.f;
#pragma unroll
  for (int r = 0; r < 16; ++r) sab += fabsf(acc[r]);
  sab += __shfl_xor(sab, 32);
  if (l < 32) rowpart[w][ln] = sab;
  __syncthreads();
  const float rsum = rowpart[grp * 4 + 0][ln] + rowpart[grp * 4 + 1][ln] +
                     rowpart[grp * 4 + 2][ln] + rowpart[grp * 4 + 3][ln];
  const float rinv = 1.f / fmaxf(rsum, EPSN);
  float basen[16];
#pragma unroll
  for (int r = 0; r < 16; ++r) basen[r] = acc[r] * rinv;

  __syncthreads();
  stageWf(Wmf, WL, t);
  __syncthreads();
#pragma unroll
  for (int r = 0; r < 16; ++r) acc[r] = 0.f;
#pragma unroll
  for (int kc = 0; kc < 8; ++kc)
    acc = __builtin_amdgcn_mfma_f32_32x32x16_bf16(
        wfrag(WL, cq * 32 + ln, kc, lh), bfA[kc], acc, 0, 0, 0);
#pragma unroll
  for (int r = 0; r < 16; ++r) {
    int c = cq * 32 + (r & 3) + 8 * (r >> 2) + 4 * lh;
    Mb[lrow][(((c >> 3) ^ (ln & 15)) << 3) + (c & 7)] = f2b(acc[r] + blds[0][c]);
  }
  __syncthreads();

  stageWf(Wsf, WL, t);
  __syncthreads();
#pragma unroll
  for (int r = 0; r < 16; ++r) acc[r] = 0.f;
#pragma unroll
  for (int kc = 0; kc < 8; ++kc)
    acc = __builtin_amdgcn_mfma_f32_32x32x16_bf16(
        wfrag(WL, cq * 32 + ln, kc, lh), bfS[kc], acc, 0, 0, 0);
#pragma unroll
  for (int r = 0; r < 16; ++r) {
    int c = cq * 32 + (r & 3) + 8 * (r >> 2) + 4 * lh;
    Sb[lrow][(((c >> 3) ^ (ln & 15)) << 3) + (c & 7)] = f2b(acc[r] + blds[1][c]);
  }
  __syncthreads();

  stageWf(Wg1f, WL, t);
  __syncthreads();
#pragma unroll
  for (int r = 0; r < 16; ++r) acc[r] = 0.f;
#pragma unroll
  for (int kc = 0; kc < 8; ++kc)
    acc = __builtin_amdgcn_mfma_f32_32x32x16_bf16(
        wfrag(WL, cq * 32 + ln, kc, lh), wfrag(Mb, lrow, kc, lh), acc, 0, 0, 0);
  __syncthreads();
  stageWf(Wg2f, WL, t);
  __syncthreads();
#pragma unroll
  for (int kc = 0; kc < 8; ++kc)
    acc = __builtin_amdgcn_mfma_f32_32x32x16_bf16(
        wfrag(WL, cq * 32 + ln, kc, lh), wfrag(Sb, lrow, kc, lh), acc, 0, 0, 0);

  float val[16];
#pragma unroll
  for (int r = 0; r < 16; ++r) {
    int c = cq * 32 + (r & 3) + 8 * (r >> 2) + 4 * lh;
    float z = acc[r] + blds[2][c];
    float g = 1.f / (1.f + __expf(-z));
    int off = (((c >> 3) ^ (ln & 15)) << 3) + (c & 7);
    float mv = b2f(Mb[lrow][off]);
    float sv = b2f(Sb[lrow][off]);
    val[r] = basen[r] + g * mv + (1.f - g) * sv;
  }

  const int orow = t >> 3, c0 = (t & 7) * 4;
  if (outNorm) {
    __syncthreads();
#pragma unroll
    for (int r = 0; r < 16; ++r)
      tr[lrow][cq * 32 + (r & 3) + 8 * (r >> 2) + 4 * lh] = basen[r];
    __syncthreads();
#pragma unroll
    for (int q = 0; q < 4; ++q)
      *(float4*)&outNorm[(size_t)(i0 + orow) * DD + c0 + 32 * q] =
          *(const float4*)&tr[orow][c0 + 32 * q];
  }
  __syncthreads();
#pragma unroll
  for (int r = 0; r < 16; ++r)
    tr[lrow][cq * 32 + (r & 3) + 8 * (r >> 2) + 4 * lh] = val[r];
  __syncthreads();
  if (outValF) {
#pragma unroll
    for (int q = 0; q < 4; ++q)
      *(float4*)&outValF[(size_t)(i0 + orow) * DD + c0 + 32 * q] =
          *(const float4*)&tr[orow][c0 + 32 * q];
  }
  if (outValB) {
#pragma unroll
    for (int q = 0; q < 4; ++q) {
      float4 v = *(const float4*)&tr[orow][c0 + 32 * q];
      ushort4 o;
      o.x = f2b(v.x); o.y = f2b(v.y); o.z = f2b(v.z); o.w = f2b(v.w);
      *(ushort4*)&outValB[(size_t)(i0 + orow) * DD + c0 + 32 * q] = o;
    }
  }
}

// ---------------------------------------------------------------------------
extern "C" void kernel_launch(void* const* d_in, const int* in_sizes, int n_in,
                              void* d_out, int out_size, void* d_ws,
                              size_t ws_size, hipStream_t stream) {
  const float* f1 = (const float*)d_in[0];
  const float* f2 = (const float*)d_in[1];
  const float* Wd1 = (const float*)d_in[2];
  const float* bd1 = (const float*)d_in[3];
  const float* Wd2 = (const float*)d_in[4];
  const float* bd2 = (const float*)d_in[5];
  const float* Ws1 = (const float*)d_in[6];
  const float* bs1 = (const float*)d_in[7];
  const float* Ws2 = (const float*)d_in[8];
  const float* bs2 = (const float*)d_in[9];
  const float* g1W1 = (const float*)d_in[10];
  const float* g1b1 = (const float*)d_in[11];
  const float* g1W2 = (const float*)d_in[12];
  const float* g1b2 = (const float*)d_in[13];
  const float* g2W1 = (const float*)d_in[14];
  const float* g2b1 = (const float*)d_in[15];
  const float* g2W2 = (const float*)d_in[16];
  const float* g2b2 = (const float*)d_in[17];

  const int N = in_sizes[0] / DD;  // 8192
  const size_t ND = (size_t)N * DD;

  float* ws = (float*)d_ws;
  float* T1 = ws;                                   // DD*DD f
  float* T2 = T1 + DD * DD;                         // DD*DD f
  float* rbp = T2 + DD * DD;                        // 8*N f
  unsigned short* f1bb = (unsigned short*)(rbp + 8 * (size_t)N);
  unsigned short* f2bb = f1bb + ND;
  unsigned short* f1nb = f2bb + ND;
  unsigned short* Hps = f1nb + ND;                  // 6*ND shorts (12MB)
  float* Tpart = (float*)Hps;                       // 128*DD*DD f (8MB, dead
                                                    // before attn writes Hps)
  float* out0 = (float*)d_out;
  float* out1 = out0 + ND;

  // Gram partials (atomic-free) + bf16 emission, then slice reduce
  k_ata_part<<<dim3(2, 2, 128), 256, 0, stream>>>(f1, f2, Tpart, f1bb, f2bb,
                                                  N / 64);
  k_tred<<<dim3(16, 2), 256, 0, stream>>>(Tpart, T1, T2);

  // --- message block 1: d2 -> d1 ---
  k_attn<<<dim3(N / 64, JSPLIT), 256, 0, stream>>>(
      f1bb, f2bb, Hps, (unsigned short*)out0, rbp, N);
  k_post<<<N / 64, 512, 0, stream>>>(Hps, (unsigned short*)out0, rbp, f2bb,
                                     f1bb, T1, Wd1, bd1, Ws1, bs1, g1W1, g1b1,
                                     g1W2, g1b2, out0, nullptr, f1nb, N);

  // --- message block 2: d1 -> d2 ---
  k_attn<<<dim3(N / 64, JSPLIT), 256, 0, stream>>>(
      f2bb, f1nb, Hps, (unsigned short*)out1, rbp, N);
  k_post<<<N / 64, 512, 0, stream>>>(Hps, (unsigned short*)out1, rbp, f1nb,
                                     f2bb, T2, Wd2, bd2, Ws2, bs2, g2W1, g2b1,
                                     g2W2, g2b2, nullptr, out1, nullptr, N);
}

// Round 16
// 154.758 us; speedup vs baseline: 5.3584x; 5.3584x over previous
//
#include <hip/hip_runtime.h>
#include <hip/hip_bf16.h>

#define DD 128
#define EPSN 1e-12f
#define JSPLIT 8

typedef __attribute__((ext_vector_type(8))) short bf16x8;
typedef __attribute__((ext_vector_type(16))) float f32x16;

__device__ __forceinline__ unsigned short f2b(float f) {
  unsigned int u = __builtin_bit_cast(unsigned int, f);
  return (unsigned short)((u + 0x7fffu + ((u >> 16) & 1u)) >> 16);
}
__device__ __forceinline__ float b2f(unsigned short u) {
  unsigned int v = ((unsigned int)u) << 16;
  return __builtin_bit_cast(float, v);
}

// ---------------------------------------------------------------------------
// T-partials for BOTH tensors, atomic-free (R13-exact, proven).
// grid(2,2,128) x 256.
// ---------------------------------------------------------------------------
__global__ __launch_bounds__(256) void k_ata_part(
    const float* __restrict__ f1, const float* __restrict__ f2,
    float* __restrict__ Tpart,
    unsigned short* __restrict__ b1, unsigned short* __restrict__ b2,
    int chunkRows) {
  __shared__ float si[128][64];
  __shared__ float sj[128][64];
  const int sel = blockIdx.z >> 6;
  const int zc = blockIdx.z & 63;
  const float* X = sel ? f2 : f1;
  unsigned short* Xb16 = sel ? b2 : b1;
  const int bi = blockIdx.x, bj = blockIdx.y;
  const int n0 = zc * chunkRows;
  const int t = threadIdx.x;
  const bool emit = (bi == 0) && (bj == 1);
  for (int idx = t; idx < 128 * 16; idx += 256) {
    int r = idx >> 4, c4 = idx & 15;
    float4 a = *((const float4*)(X + (size_t)(n0 + r) * DD + bi * 64) + c4);
    float4 b = *((const float4*)(X + (size_t)(n0 + r) * DD + bj * 64) + c4);
    *(float4*)&si[r][c4 * 4] = a;
    *(float4*)&sj[r][c4 * 4] = b;
    if (emit) {
      ushort4 oa, ob;
      oa.x = f2b(a.x); oa.y = f2b(a.y); oa.z = f2b(a.z); oa.w = f2b(a.w);
      ob.x = f2b(b.x); ob.y = f2b(b.y); ob.z = f2b(b.z); ob.w = f2b(b.w);
      *(ushort4*)&Xb16[(size_t)(n0 + r) * DD + c4 * 4] = oa;
      *(ushort4*)&Xb16[(size_t)(n0 + r) * DD + 64 + c4 * 4] = ob;
    }
  }
  __syncthreads();
  const int tx = t & 15, ty = t >> 4;
  float acc[4][4] = {};
  for (int n = 0; n < 128; ++n) {
    float4 av = *(const float4*)&si[n][ty * 4];
    float4 bv = *(const float4*)&sj[n][tx * 4];
    float a[4] = {av.x, av.y, av.z, av.w};
    float b[4] = {bv.x, bv.y, bv.z, bv.w};
#pragma unroll
    for (int i = 0; i < 4; ++i)
#pragma unroll
      for (int j = 0; j < 4; ++j) acc[i][j] += a[i] * b[j];
  }
  float* tp = Tpart + (size_t)(sel * 64 + zc) * (DD * DD);
#pragma unroll
  for (int i = 0; i < 4; ++i) {
    float4 v = make_float4(acc[i][0], acc[i][1], acc[i][2], acc[i][3]);
    *(float4*)&tp[(size_t)(bi * 64 + ty * 4 + i) * DD + bj * 64 + tx * 4] = v;
  }
}

// ---------------------------------------------------------------------------
// Reduce 64 T-partial slices -> T (both tensors).  grid(16, 2) x 256.
// ---------------------------------------------------------------------------
__global__ __launch_bounds__(256) void k_tred(const float* __restrict__ Tpart,
                                              float* __restrict__ T1,
                                              float* __restrict__ T2) {
  const int sel = blockIdx.y;
  const int e0 = (blockIdx.x * 256 + threadIdx.x) * 4;
  const float* base = Tpart + (size_t)sel * 64 * (DD * DD);
  float4 s = make_float4(0.f, 0.f, 0.f, 0.f);
#pragma unroll
  for (int z = 0; z < 64; ++z) {
    float4 v = *(const float4*)(base + (size_t)z * (DD * DD) + e0);
    s.x += v.x; s.y += v.y; s.z += v.z; s.w += v.w;
  }
  float* T = sel ? T2 : T1;
  *(float4*)&T[e0] = s;
}

// ---------------------------------------------------------------------------
// MFMA fused attention — R14 structure (64 i-rows / 256 threads, 40KB LDS,
// 4 blocks/CU) but WITHOUT the occupancy clamp that forced 64-VGPR spills.
// grid(N/64, JSPLIT) x 256.
// ---------------------------------------------------------------------------
__global__ __launch_bounds__(256) void k_attn(
    const unsigned short* __restrict__ Xb, const unsigned short* __restrict__ Yb,
    unsigned short* __restrict__ Hps, unsigned short* __restrict__ Hx,
    float* __restrict__ rbp, int N) {
  __shared__ __align__(16) char LP[40960];
  unsigned short* Yst = (unsigned short*)LP;   // [2][10240] tr-subtiles (40KB)
  unsigned short* mrgb = (unsigned short*)LP;  // epilogue [64][128] bf16 16KB
  float* rs = (float*)(LP + 16384);            // epilogue [2][32] rowabs merge
  const int t = threadIdx.x;
  const int w = t >> 6, l = t & 63, lh = l >> 5, ln = l & 31;
  const int wb = w >> 1, jh = w & 1;  // wb in 0..1 (64 i-rows/block)
  const int i0 = blockIdx.x * 64;
  const size_t ND = (size_t)N * DD;
  const int jbase = blockIdx.y * (N / JSPLIT);
  const int jiters = (N / JSPLIT) / 64;

  // X fragments in registers (loop-invariant)
  const int xrow = i0 + wb * 32 + ln;
  bf16x8 xf[8];
#pragma unroll
  for (int kc = 0; kc < 8; ++kc)
    xf[kc] = *(const bf16x8*)(Xb + (size_t)xrow * DD + kc * 16 + lh * 8);

  f32x16 acc2[4];
#pragma unroll
  for (int cb = 0; cb < 4; ++cb)
#pragma unroll
    for (int r = 0; r < 16; ++r) acc2[cb][r] = 0.f;
  float rsum = 0.f;

  // staging: 256 threads x 4 chunks; thread t -> row sjj, chunks ch0+4c
  const int sjj = t >> 2;
  const int ch0 = t & 3;
  const int SB = sjj >> 2;
  bf16x8 rg[4];
  {
    const unsigned short* yb = Yb + (size_t)(jbase + sjj) * DD + ch0 * 8;
#pragma unroll
    for (int c = 0; c < 4; ++c) rg[c] = *(const bf16x8*)(yb + 32 * c);
  }
#pragma unroll
  for (int c = 0; c < 4; ++c) {
    int ch = ch0 + 4 * c;
    int blk = SB * 8 + ((ch >> 1) ^ (SB & 7));
    int eoff = 80 * blk + (sjj & 3) * 16 + (((ch & 1) ^ (SB & 1)) << 3);
    *(bf16x8*)&Yst[eoff] = rg[c];
  }

  const unsigned ystBase0 = (unsigned)(size_t)Yst;
  const int d4b = ln >> 4;
  const int xrb = (ln & 15) << 1;
  const int yr = jh * 32 + ln;
  const int YB = yr >> 2;

  for (int jt = 0; jt < jiters; ++jt) {
    const int cur = jt & 1;
    __syncthreads();  // buf[cur] writes visible; prev readers done
    // ---- EARLY: issue ph2 B tr-reads (depend only on staged tile)
    const unsigned yB = ystBase0 + (unsigned)(cur * 20480);
    uint2 tvv[2][4][2];
#pragma unroll
    for (int f = 0; f < 2; ++f)
#pragma unroll
      for (int h2 = 0; h2 < 2; ++h2) {
        const int B = jh * 8 + f * 4 + lh * 2 + h2;
        const int b7 = B & 7;
        const unsigned xr2 = (unsigned)(xrb ^ (h2 << 4));
#pragma unroll
        for (int cb = 0; cb < 4; ++cb) {
          int blk = B * 8 + ((cb * 2 + d4b) ^ b7);
          unsigned a = yB + (unsigned)(blk * 160) + xr2;
          asm volatile("ds_read_b64_tr_b16 %0, %1"
                       : "=v"(tvv[f][cb][h2])
                       : "v"(a));
        }
      }
    // T14: prefetch next Y tile into regs
    if (jt + 1 < jiters) {
      const unsigned short* yb =
          Yb + (size_t)(jbase + (jt + 1) * 64 + sjj) * DD + ch0 * 8;
#pragma unroll
      for (int c = 0; c < 4; ++c) rg[c] = *(const bf16x8*)(yb + 32 * c);
    }
    // ---- ph1 (swapped): lane ln holds S-row i; two MFMA chains
    f32x16 s0, s1;
#pragma unroll
    for (int r = 0; r < 16; ++r) { s0[r] = 0.f; s1[r] = 0.f; }
#pragma unroll
    for (int kc = 0; kc < 8; ++kc) {
      int ck = kc * 2 + lh;
      int off = 80 * (YB * 8 + ((ck >> 1) ^ (YB & 7))) + (yr & 3) * 16 +
                (((ck & 1) ^ (YB & 1)) << 3);
      bf16x8 yv = *(const bf16x8*)&Yst[cur * 10240 + off];
      if (kc & 1)
        s1 = __builtin_amdgcn_mfma_f32_32x32x16_bf16(yv, xf[kc], s1, 0, 0, 0);
      else
        s0 = __builtin_amdgcn_mfma_f32_32x32x16_bf16(yv, xf[kc], s0, 0, 0, 0);
    }
    f32x16 s;
#pragma unroll
    for (int r = 0; r < 16; ++r) s[r] = s0[r] + s1[r];
    // ---- diag zero (tile-on-diagonal only)
    const int j0g = jbase + jt * 64 + jh * 32;
    if (i0 + wb * 32 == j0g) {
#pragma unroll
      for (int r = 0; r < 16; ++r) {
        int jl = (r & 3) + 8 * (r >> 2) + 4 * lh;
        if (jl == ln) s[r] = 0.f;
      }
    }
    // ---- rowabs (lane-local row)
#pragma unroll
    for (int r = 0; r < 16; ++r) rsum += fabsf(s[r]);
    // ---- pack S row to bf16 fragments (cvt_pk + permlane32_swap)
    unsigned pq[8];
#pragma unroll
    for (int q = 0; q < 8; ++q)
      asm("v_cvt_pk_bf16_f32 %0, %1, %2"
          : "=v"(pq[q])
          : "v"(s[2 * q]), "v"(s[2 * q + 1]));
    bf16x8 av2[2];
#pragma unroll
    for (int f = 0; f < 2; ++f) {
      unsigned a0 = pq[4 * f + 0], b0 = pq[4 * f + 2];
      unsigned a1 = pq[4 * f + 1], b1 = pq[4 * f + 3];
      asm volatile("v_permlane32_swap_b32 %0, %1" : "+v"(a0), "+v"(b0));
      asm volatile("v_permlane32_swap_b32 %0, %1" : "+v"(a1), "+v"(b1));
      av2[f] = __builtin_bit_cast(bf16x8, make_uint4(a0, a1, b0, b1));
    }
    // ---- drain tr reads, fence, ph2 MFMAs (rule #18)
    asm volatile("s_waitcnt lgkmcnt(0)" ::: "memory");
    __builtin_amdgcn_sched_barrier(0);
#pragma unroll
    for (int f = 0; f < 2; ++f)
#pragma unroll
      for (int cb = 0; cb < 4; ++cb) {
        bf16x8 bv = __builtin_bit_cast(
            bf16x8, make_uint4(tvv[f][cb][0].x, tvv[f][cb][0].y,
                               tvv[f][cb][1].x, tvv[f][cb][1].y));
        acc2[cb] =
            __builtin_amdgcn_mfma_f32_32x32x16_bf16(av2[f], bv, acc2[cb], 0, 0, 0);
      }
    // ---- write prefetched regs -> buf[cur^1]
    if (jt + 1 < jiters) {
      int bo = (cur ^ 1) * 10240;
#pragma unroll
      for (int c = 0; c < 4; ++c) {
        int ch = ch0 + 4 * c;
        int blk = SB * 8 + ((ch >> 1) ^ (SB & 7));
        int eoff = bo + 80 * blk + (sjj & 3) * 16 + (((ch & 1) ^ (SB & 1)) << 3);
        *(bf16x8*)&Yst[eoff] = rg[c];
      }
    }
  }
  // ---- epilogue: merge j-halves in LDS (bf16, aliases dead Yst)
  rsum += __shfl_xor(rsum, 32);
  __syncthreads();
  if (jh == 1) {
#pragma unroll
    for (int cb = 0; cb < 4; ++cb)
#pragma unroll
      for (int r = 0; r < 16; ++r) {
        int rl = (r & 3) + 8 * (r >> 2) + 4 * lh;
        mrgb[(wb * 32 + rl) * 128 + cb * 32 + ln] = f2b(acc2[cb][r]);
      }
    if (l < 32) rs[wb * 32 + ln] = rsum;
  }
  __syncthreads();
  if (jh == 0) {
    unsigned short* hp;
    int rstr;
    if (blockIdx.y < 6) {
      hp = Hps + (size_t)blockIdx.y * ND;
      rstr = 128;
    } else {
      hp = Hx + (blockIdx.y - 6) * 128;
      rstr = 256;
    }
#pragma unroll
    for (int cb = 0; cb < 4; ++cb)
#pragma unroll
      for (int r = 0; r < 16; ++r) {
        int rl = (r & 3) + 8 * (r >> 2) + 4 * lh;
        float v = acc2[cb][r] + b2f(mrgb[(wb * 32 + rl) * 128 + cb * 32 + ln]);
        hp[(size_t)(i0 + wb * 32 + rl) * rstr + cb * 32 + ln] = f2b(v);
      }
    if (l < 32)
      rbp[(size_t)blockIdx.y * N + i0 + wb * 32 + ln] = rsum + rs[wb * 32 + ln];
  }
}

// ---------------------------------------------------------------------------
// Fused post-attention chain, 64 rows/block (R12/R13-exact, proven).
// ---------------------------------------------------------------------------
__device__ __forceinline__ void stageWf(const float* __restrict__ g,
                                        unsigned short (*L)[128], int t) {
#pragma unroll
  for (int idx = t; idx < 2048; idx += 512) {
    int r = idx >> 4, ch = idx & 15;
    const float* p = g + r * 128 + ch * 8;
    float4 u = *(const float4*)p, v = *(const float4*)(p + 4);
    bf16x8 o;
    o[0] = (short)f2b(u.x); o[1] = (short)f2b(u.y);
    o[2] = (short)f2b(u.z); o[3] = (short)f2b(u.w);
    o[4] = (short)f2b(v.x); o[5] = (short)f2b(v.y);
    o[6] = (short)f2b(v.z); o[7] = (short)f2b(v.w);
    *(bf16x8*)&L[r][(ch ^ (r & 15)) << 3] = o;
  }
}
__device__ __forceinline__ bf16x8 wfrag(const unsigned short (*L)[128], int row,
                                        int kc, int lh) {
  int ch = kc * 2 + lh;
  return *(const bf16x8*)&L[row][(ch ^ (row & 15)) << 3];
}

__global__ __launch_bounds__(512) void k_post(
    const unsigned short* __restrict__ Hps, const unsigned short* __restrict__ Hx,
    const float* __restrict__ rbp, const unsigned short* __restrict__ fselfb,
    const unsigned short* __restrict__ fbaseb,
    const float* __restrict__ Tf,
    const float* __restrict__ Wmf, const float* __restrict__ bm,
    const float* __restrict__ Wsf, const float* __restrict__ bs,
    const float* __restrict__ Wg1f, const float* __restrict__ bg1,
    const float* __restrict__ Wg2f, const float* __restrict__ bg2,
    float* __restrict__ outNorm, float* __restrict__ outValF,
    unsigned short* __restrict__ outValB, int N) {
  __shared__ unsigned short WL[128][128];
  __shared__ __align__(16) char pool[64 * 132 * 4];
  __shared__ float blds[3][128];
  __shared__ float rowpart[8][32];
  unsigned short(*Mb)[128] = (unsigned short(*)[128])pool;
  unsigned short(*Sb)[128] = (unsigned short(*)[128])(pool + 16384);
  float(*tr)[132] = (float(*)[132])pool;
  float(*hs)[132] = (float(*)[132])pool;

  const int t = threadIdx.x;
  const int w = t >> 6, l = t & 63, ln = l & 31, lh = l >> 5;
  const int grp = w >> 2, cq = w & 3;
  const int i0 = blockIdx.x * 64;
  const int lrow = grp * 32 + ln;
  const int row = i0 + lrow;
  const size_t ND = (size_t)N * DD;

  for (int idx = t; idx < 1024; idx += 512) {
    int r = idx >> 4, c8 = idx & 15;
    float a8[8] = {0.f, 0.f, 0.f, 0.f, 0.f, 0.f, 0.f, 0.f};
#pragma unroll
    for (int sp = 0; sp < 8; ++sp) {
      const unsigned short* p =
          (sp < 6) ? Hps + (size_t)sp * ND + (size_t)(i0 + r) * DD + c8 * 8
                   : Hx + (size_t)(i0 + r) * 256 + (sp - 6) * 128 + c8 * 8;
      bf16x8 v = *(const bf16x8*)p;
#pragma unroll
      for (int e = 0; e < 8; ++e) a8[e] += b2f((unsigned short)v[e]);
    }
    *(float4*)&hs[r][c8 * 8] = make_float4(a8[0], a8[1], a8[2], a8[3]);
    *(float4*)&hs[r][c8 * 8 + 4] = make_float4(a8[4], a8[5], a8[6], a8[7]);
  }
  if (t < 128) {
    blds[0][t] = bm[t];
    blds[1][t] = bs[t];
    blds[2][t] = bg1[t] + bg2[t];
  }
  stageWf(Tf, WL, t);
  __syncthreads();

  float rbv = 0.f;
#pragma unroll
  for (int sp = 0; sp < 8; ++sp) rbv += rbp[(size_t)sp * N + row];
  const float sc = (1.f / (float)N) / fmaxf(rbv, EPSN);
  bf16x8 bfA[8], bfS[8], bfB[8];
#pragma unroll
  for (int kc = 0; kc < 8; ++kc) {
    const float* hp = &hs[lrow][kc * 16 + lh * 8];
    float4 u = *(const float4*)hp;
    float4 v = *(const float4*)(hp + 4);
    bf16x8 a;
    a[0] = (short)f2b(u.x * sc); a[1] = (short)f2b(u.y * sc);
    a[2] = (short)f2b(u.z * sc); a[3] = (short)f2b(u.w * sc);
    a[4] = (short)f2b(v.x * sc); a[5] = (short)f2b(v.y * sc);
    a[6] = (short)f2b(v.z * sc); a[7] = (short)f2b(v.w * sc);
    bfA[kc] = a;
    bfS[kc] = *(const bf16x8*)(fselfb + (size_t)row * DD + kc * 16 + lh * 8);
    bfB[kc] = *(const bf16x8*)(fbaseb + (size_t)row * DD + kc * 16 + lh * 8);
  }

  f32x16 acc;
#pragma unroll
  for (int r = 0; r < 16; ++r) acc[r] = 0.f;
#pragma unroll
  for (int kc = 0; kc < 8; ++kc)
    acc = __builtin_amdgcn_mfma_f32_32x32x16_bf16(
        wfrag(WL, cq * 32 + ln, kc, lh), bfB[kc], acc, 0, 0, 0);
  float sab = 0.f;
#pragma unroll
  for (int r = 0; r < 16; ++r) sab += fabsf(acc[r]);
  sab += __shfl_xor(sab, 32);
  if (l < 32) rowpart[w][ln] = sab;
  __syncthreads();
  const float rsum = rowpart[grp * 4 + 0][ln] + rowpart[grp * 4 + 1][ln] +
                     rowpart[grp * 4 + 2][ln] + rowpart[grp * 4 + 3][ln];
  const float rinv = 1.f / fmaxf(rsum, EPSN);
  float basen[16];
#pragma unroll
  for (int r = 0; r < 16; ++r) basen[r] = acc[r] * rinv;

  __syncthreads();
  stageWf(Wmf, WL, t);
  __syncthreads();
#pragma unroll
  for (int r = 0; r < 16; ++r) acc[r] = 0.f;
#pragma unroll
  for (int kc = 0; kc < 8; ++kc)
    acc = __builtin_amdgcn_mfma_f32_32x32x16_bf16(
        wfrag(WL, cq * 32 + ln, kc, lh), bfA[kc], acc, 0, 0, 0);
#pragma unroll
  for (int r = 0; r < 16; ++r) {
    int c = cq * 32 + (r & 3) + 8 * (r >> 2) + 4 * lh;
    Mb[lrow][(((c >> 3) ^ (ln & 15)) << 3) + (c & 7)] = f2b(acc[r] + blds[0][c]);
  }
  __syncthreads();

  stageWf(Wsf, WL, t);
  __syncthreads();
#pragma unroll
  for (int r = 0; r < 16; ++r) acc[r] = 0.f;
#pragma unroll
  for (int kc = 0; kc < 8; ++kc)
    acc = __builtin_amdgcn_mfma_f32_32x32x16_bf16(
        wfrag(WL, cq * 32 + ln, kc, lh), bfS[kc], acc, 0, 0, 0);
#pragma unroll
  for (int r = 0; r < 16; ++r) {
    int c = cq * 32 + (r & 3) + 8 * (r >> 2) + 4 * lh;
    Sb[lrow][(((c >> 3) ^ (ln & 15)) << 3) + (c & 7)] = f2b(acc[r] + blds[1][c]);
  }
  __syncthreads();

  stageWf(Wg1f, WL, t);
  __syncthreads();
#pragma unroll
  for (int r = 0; r < 16; ++r) acc[r] = 0.f;
#pragma unroll
  for (int kc = 0; kc < 8; ++kc)
    acc = __builtin_amdgcn_mfma_f32_32x32x16_bf16(
        wfrag(WL, cq * 32 + ln, kc, lh), wfrag(Mb, lrow, kc, lh), acc, 0, 0, 0);
  __syncthreads();
  stageWf(Wg2f, WL, t);
  __syncthreads();
#pragma unroll
  for (int kc = 0; kc < 8; ++kc)
    acc = __builtin_amdgcn_mfma_f32_32x32x16_bf16(
        wfrag(WL, cq * 32 + ln, kc, lh), wfrag(Sb, lrow, kc, lh), acc, 0, 0, 0);

  float val[16];
#pragma unroll
  for (int r = 0; r < 16; ++r) {
    int c = cq * 32 + (r & 3) + 8 * (r >> 2) + 4 * lh;
    float z = acc[r] + blds[2][c];
    float g = 1.f / (1.f + __expf(-z));
    int off = (((c >> 3) ^ (ln & 15)) << 3) + (c & 7);
    float mv = b2f(Mb[lrow][off]);
    float sv = b2f(Sb[lrow][off]);
    val[r] = basen[r] + g * mv + (1.f - g) * sv;
  }

  const int orow = t >> 3, c0 = (t & 7) * 4;
  if (outNorm) {
    __syncthreads();
#pragma unroll
    for (int r = 0; r < 16; ++r)
      tr[lrow][cq * 32 + (r & 3) + 8 * (r >> 2) + 4 * lh] = basen[r];
    __syncthreads();
#pragma unroll
    for (int q = 0; q < 4; ++q)
      *(float4*)&outNorm[(size_t)(i0 + orow) * DD + c0 + 32 * q] =
          *(const float4*)&tr[orow][c0 + 32 * q];
  }
  __syncthreads();
#pragma unroll
  for (int r = 0; r < 16; ++r)
    tr[lrow][cq * 32 + (r & 3) + 8 * (r >> 2) + 4 * lh] = val[r];
  __syncthreads();
  if (outValF) {
#pragma unroll
    for (int q = 0; q < 4; ++q)
      *(float4*)&outValF[(size_t)(i0 + orow) * DD + c0 + 32 * q] =
          *(const float4*)&tr[orow][c0 + 32 * q];
  }
  if (outValB) {
#pragma unroll
    for (int q = 0; q < 4; ++q) {
      float4 v = *(const float4*)&tr[orow][c0 + 32 * q];
      ushort4 o;
      o.x = f2b(v.x); o.y = f2b(v.y); o.z = f2b(v.z); o.w = f2b(v.w);
      *(ushort4*)&outValB[(size_t)(i0 + orow) * DD + c0 + 32 * q] = o;
    }
  }
}

// ---------------------------------------------------------------------------
extern "C" void kernel_launch(void* const* d_in, const int* in_sizes, int n_in,
                              void* d_out, int out_size, void* d_ws,
                              size_t ws_size, hipStream_t stream) {
  const float* f1 = (const float*)d_in[0];
  const float* f2 = (const float*)d_in[1];
  const float* Wd1 = (const float*)d_in[2];
  const float* bd1 = (const float*)d_in[3];
  const float* Wd2 = (const float*)d_in[4];
  const float* bd2 = (const float*)d_in[5];
  const float* Ws1 = (const float*)d_in[6];
  const float* bs1 = (const float*)d_in[7];
  const float* Ws2 = (const float*)d_in[8];
  const float* bs2 = (const float*)d_in[9];
  const float* g1W1 = (const float*)d_in[10];
  const float* g1b1 = (const float*)d_in[11];
  const float* g1W2 = (const float*)d_in[12];
  const float* g1b2 = (const float*)d_in[13];
  const float* g2W1 = (const float*)d_in[14];
  const float* g2b1 = (const float*)d_in[15];
  const float* g2W2 = (const float*)d_in[16];
  const float* g2b2 = (const float*)d_in[17];

  const int N = in_sizes[0] / DD;  // 8192
  const size_t ND = (size_t)N * DD;

  float* ws = (float*)d_ws;
  float* T1 = ws;                                   // DD*DD f
  float* T2 = T1 + DD * DD;                         // DD*DD f
  float* rbp = T2 + DD * DD;                        // 8*N f
  unsigned short* f1bb = (unsigned short*)(rbp + 8 * (size_t)N);
  unsigned short* f2bb = f1bb + ND;
  unsigned short* f1nb = f2bb + ND;
  unsigned short* Hps = f1nb + ND;                  // 6*ND shorts (12MB)
  float* Tpart = (float*)Hps;                       // 128*DD*DD f (8MB, dead
                                                    // before attn writes Hps)
  float* out0 = (float*)d_out;
  float* out1 = out0 + ND;

  // Gram partials (atomic-free) + bf16 emission, then slice reduce
  k_ata_part<<<dim3(2, 2, 128), 256, 0, stream>>>(f1, f2, Tpart, f1bb, f2bb,
                                                  N / 64);
  k_tred<<<dim3(16, 2), 256, 0, stream>>>(Tpart, T1, T2);

  // --- message block 1: d2 -> d1 ---
  k_attn<<<dim3(N / 64, JSPLIT), 256, 0, stream>>>(
      f1bb, f2bb, Hps, (unsigned short*)out0, rbp, N);
  k_post<<<N / 64, 512, 0, stream>>>(Hps, (unsigned short*)out0, rbp, f2bb,
                                     f1bb, T1, Wd1, bd1, Ws1, bs1, g1W1, g1b1,
                                     g1W2, g1b2, out0, nullptr, f1nb, N);

  // --- message block 2: d1 -> d2 ---
  k_attn<<<dim3(N / 64, JSPLIT), 256, 0, stream>>>(
      f2bb, f1nb, Hps, (unsigned short*)out1, rbp, N);
  k_post<<<N / 64, 512, 0, stream>>>(Hps, (unsigned short*)out1, rbp, f1nb,
                                     f2bb, T2, Wd2, bd2, Ws2, bs2, g2W1, g2b1,
                                     g2W2, g2b2, nullptr, out1, nullptr, N);
}

// Round 17
// 143.626 us; speedup vs baseline: 5.7737x; 1.0775x over previous
//
#include <hip/hip_runtime.h>
#include <hip/hip_bf16.h>

#define DD 128
#define EPSN 1e-12f
#define JSPLIT 8

typedef __attribute__((ext_vector_type(8))) short bf16x8;
typedef __attribute__((ext_vector_type(16))) float f32x16;

__device__ __forceinline__ unsigned short f2b(float f) {
  unsigned int u = __builtin_bit_cast(unsigned int, f);
  return (unsigned short)((u + 0x7fffu + ((u >> 16) & 1u)) >> 16);
}
__device__ __forceinline__ float b2f(unsigned short u) {
  unsigned int v = ((unsigned int)u) << 16;
  return __builtin_bit_cast(float, v);
}

// ---------------------------------------------------------------------------
// T-partials for BOTH tensors, atomic-free (R13-exact, proven).
// grid(2,2,128) x 256.
// ---------------------------------------------------------------------------
__global__ __launch_bounds__(256) void k_ata_part(
    const float* __restrict__ f1, const float* __restrict__ f2,
    float* __restrict__ Tpart,
    unsigned short* __restrict__ b1, unsigned short* __restrict__ b2,
    int chunkRows) {
  __shared__ float si[128][64];
  __shared__ float sj[128][64];
  const int sel = blockIdx.z >> 6;
  const int zc = blockIdx.z & 63;
  const float* X = sel ? f2 : f1;
  unsigned short* Xb16 = sel ? b2 : b1;
  const int bi = blockIdx.x, bj = blockIdx.y;
  const int n0 = zc * chunkRows;
  const int t = threadIdx.x;
  const bool emit = (bi == 0) && (bj == 1);
  for (int idx = t; idx < 128 * 16; idx += 256) {
    int r = idx >> 4, c4 = idx & 15;
    float4 a = *((const float4*)(X + (size_t)(n0 + r) * DD + bi * 64) + c4);
    float4 b = *((const float4*)(X + (size_t)(n0 + r) * DD + bj * 64) + c4);
    *(float4*)&si[r][c4 * 4] = a;
    *(float4*)&sj[r][c4 * 4] = b;
    if (emit) {
      ushort4 oa, ob;
      oa.x = f2b(a.x); oa.y = f2b(a.y); oa.z = f2b(a.z); oa.w = f2b(a.w);
      ob.x = f2b(b.x); ob.y = f2b(b.y); ob.z = f2b(b.z); ob.w = f2b(b.w);
      *(ushort4*)&Xb16[(size_t)(n0 + r) * DD + c4 * 4] = oa;
      *(ushort4*)&Xb16[(size_t)(n0 + r) * DD + 64 + c4 * 4] = ob;
    }
  }
  __syncthreads();
  const int tx = t & 15, ty = t >> 4;
  float acc[4][4] = {};
  for (int n = 0; n < 128; ++n) {
    float4 av = *(const float4*)&si[n][ty * 4];
    float4 bv = *(const float4*)&sj[n][tx * 4];
    float a[4] = {av.x, av.y, av.z, av.w};
    float b[4] = {bv.x, bv.y, bv.z, bv.w};
#pragma unroll
    for (int i = 0; i < 4; ++i)
#pragma unroll
      for (int j = 0; j < 4; ++j) acc[i][j] += a[i] * b[j];
  }
  float* tp = Tpart + (size_t)(sel * 64 + zc) * (DD * DD);
#pragma unroll
  for (int i = 0; i < 4; ++i) {
    float4 v = make_float4(acc[i][0], acc[i][1], acc[i][2], acc[i][3]);
    *(float4*)&tp[(size_t)(bi * 64 + ty * 4 + i) * DD + bj * 64 + tx * 4] = v;
  }
}

// ---------------------------------------------------------------------------
// Reduce 64 T-partial slices -> T (both tensors).  grid(16, 2) x 256.
// ---------------------------------------------------------------------------
__global__ __launch_bounds__(256) void k_tred(const float* __restrict__ Tpart,
                                              float* __restrict__ T1,
                                              float* __restrict__ T2) {
  const int sel = blockIdx.y;
  const int e0 = (blockIdx.x * 256 + threadIdx.x) * 4;
  const float* base = Tpart + (size_t)sel * 64 * (DD * DD);
  float4 s = make_float4(0.f, 0.f, 0.f, 0.f);
#pragma unroll
  for (int z = 0; z < 64; ++z) {
    float4 v = *(const float4*)(base + (size_t)z * (DD * DD) + e0);
    s.x += v.x; s.y += v.y; s.z += v.z; s.w += v.w;
  }
  float* T = sel ? T2 : T1;
  *(float4*)&T[e0] = s;
}

// ---------------------------------------------------------------------------
// MFMA fused attention (R13-exact: proven 47.6us, best).  Slice-store H,
// rbp rowabs, static LDS = 64KB.  grid(N/128, JSPLIT) x 512.
// ---------------------------------------------------------------------------
__global__ __launch_bounds__(512, 2) void k_attn(
    const unsigned short* __restrict__ Xb, const unsigned short* __restrict__ Yb,
    unsigned short* __restrict__ Hps, unsigned short* __restrict__ Hx,
    float* __restrict__ rbp, int N) {
  __shared__ __align__(16) char LP[65536];
  unsigned short* Yst = (unsigned short*)LP;   // [2][10240] tr-subtiles (40KB)
  unsigned short* mrgb = (unsigned short*)LP;  // epilogue [128][128] bf16 32KB
  float* rs = (float*)(LP + 32768);            // epilogue [4][32] rowabs merge
  const int t = threadIdx.x;
  const int w = t >> 6, l = t & 63, lh = l >> 5, ln = l & 31;
  const int wb = w >> 1, jh = w & 1;
  const int i0 = blockIdx.x * 128;
  const size_t ND = (size_t)N * DD;
  const int jbase = blockIdx.y * (N / JSPLIT);
  const int jiters = (N / JSPLIT) / 64;

  const int xrow = i0 + wb * 32 + ln;
  bf16x8 xf[8];
#pragma unroll
  for (int kc = 0; kc < 8; ++kc)
    xf[kc] = *(const bf16x8*)(Xb + (size_t)xrow * DD + kc * 16 + lh * 8);

  f32x16 acc2[4];
#pragma unroll
  for (int cb = 0; cb < 4; ++cb)
#pragma unroll
    for (int r = 0; r < 16; ++r) acc2[cb][r] = 0.f;
  float rsum = 0.f;

  const int sjj = t >> 3;
  const int ch0 = t & 7;
  const int SB = sjj >> 2;
  bf16x8 rg[2];
  {
    const unsigned short* yb = Yb + (size_t)(jbase + sjj) * DD + ch0 * 8;
    rg[0] = *(const bf16x8*)yb;
    rg[1] = *(const bf16x8*)(yb + 64);
  }
#pragma unroll
  for (int c = 0; c < 2; ++c) {
    int ch = ch0 + 8 * c;
    int blk = SB * 8 + ((ch >> 1) ^ (SB & 7));
    int eoff = 80 * blk + (sjj & 3) * 16 + (((ch & 1) ^ (SB & 1)) << 3);
    *(bf16x8*)&Yst[eoff] = rg[c];
  }

  const unsigned ystBase0 = (unsigned)(size_t)Yst;
  const int d4b = ln >> 4;
  const int xrb = (ln & 15) << 1;
  const int yr = jh * 32 + ln;
  const int YB = yr >> 2;

  for (int jt = 0; jt < jiters; ++jt) {
    const int cur = jt & 1;
    __syncthreads();
    const unsigned yB = ystBase0 + (unsigned)(cur * 20480);
    uint2 tvv[2][4][2];
#pragma unroll
    for (int f = 0; f < 2; ++f)
#pragma unroll
      for (int h2 = 0; h2 < 2; ++h2) {
        const int B = jh * 8 + f * 4 + lh * 2 + h2;
        const int b7 = B & 7;
        const unsigned xr2 = (unsigned)(xrb ^ (h2 << 4));
#pragma unroll
        for (int cb = 0; cb < 4; ++cb) {
          int blk = B * 8 + ((cb * 2 + d4b) ^ b7);
          unsigned a = yB + (unsigned)(blk * 160) + xr2;
          asm volatile("ds_read_b64_tr_b16 %0, %1"
                       : "=v"(tvv[f][cb][h2])
                       : "v"(a));
        }
      }
    if (jt + 1 < jiters) {
      const unsigned short* yb =
          Yb + (size_t)(jbase + (jt + 1) * 64 + sjj) * DD + ch0 * 8;
      rg[0] = *(const bf16x8*)yb;
      rg[1] = *(const bf16x8*)(yb + 64);
    }
    f32x16 s0, s1;
#pragma unroll
    for (int r = 0; r < 16; ++r) { s0[r] = 0.f; s1[r] = 0.f; }
#pragma unroll
    for (int kc = 0; kc < 8; ++kc) {
      int ck = kc * 2 + lh;
      int off = 80 * (YB * 8 + ((ck >> 1) ^ (YB & 7))) + (yr & 3) * 16 +
                (((ck & 1) ^ (YB & 1)) << 3);
      bf16x8 yv = *(const bf16x8*)&Yst[cur * 10240 + off];
      if (kc & 1)
        s1 = __builtin_amdgcn_mfma_f32_32x32x16_bf16(yv, xf[kc], s1, 0, 0, 0);
      else
        s0 = __builtin_amdgcn_mfma_f32_32x32x16_bf16(yv, xf[kc], s0, 0, 0, 0);
    }
    f32x16 s;
#pragma unroll
    for (int r = 0; r < 16; ++r) s[r] = s0[r] + s1[r];
    const int j0g = jbase + jt * 64 + jh * 32;
    if (i0 + wb * 32 == j0g) {
#pragma unroll
      for (int r = 0; r < 16; ++r) {
        int jl = (r & 3) + 8 * (r >> 2) + 4 * lh;
        if (jl == ln) s[r] = 0.f;
      }
    }
#pragma unroll
    for (int r = 0; r < 16; ++r) rsum += fabsf(s[r]);
    unsigned pq[8];
#pragma unroll
    for (int q = 0; q < 8; ++q)
      asm("v_cvt_pk_bf16_f32 %0, %1, %2"
          : "=v"(pq[q])
          : "v"(s[2 * q]), "v"(s[2 * q + 1]));
    bf16x8 av2[2];
#pragma unroll
    for (int f = 0; f < 2; ++f) {
      unsigned a0 = pq[4 * f + 0], b0 = pq[4 * f + 2];
      unsigned a1 = pq[4 * f + 1], b1 = pq[4 * f + 3];
      asm volatile("v_permlane32_swap_b32 %0, %1" : "+v"(a0), "+v"(b0));
      asm volatile("v_permlane32_swap_b32 %0, %1" : "+v"(a1), "+v"(b1));
      av2[f] = __builtin_bit_cast(bf16x8, make_uint4(a0, a1, b0, b1));
    }
    asm volatile("s_waitcnt lgkmcnt(0)" ::: "memory");
    __builtin_amdgcn_sched_barrier(0);
#pragma unroll
    for (int f = 0; f < 2; ++f)
#pragma unroll
      for (int cb = 0; cb < 4; ++cb) {
        bf16x8 bv = __builtin_bit_cast(
            bf16x8, make_uint4(tvv[f][cb][0].x, tvv[f][cb][0].y,
                               tvv[f][cb][1].x, tvv[f][cb][1].y));
        acc2[cb] =
            __builtin_amdgcn_mfma_f32_32x32x16_bf16(av2[f], bv, acc2[cb], 0, 0, 0);
      }
    if (jt + 1 < jiters) {
      int bo = (cur ^ 1) * 10240;
#pragma unroll
      for (int c = 0; c < 2; ++c) {
        int ch = ch0 + 8 * c;
        int blk = SB * 8 + ((ch >> 1) ^ (SB & 7));
        int eoff = bo + 80 * blk + (sjj & 3) * 16 + (((ch & 1) ^ (SB & 1)) << 3);
        *(bf16x8*)&Yst[eoff] = rg[c];
      }
    }
  }
  rsum += __shfl_xor(rsum, 32);
  __syncthreads();
  if (jh == 1) {
#pragma unroll
    for (int cb = 0; cb < 4; ++cb)
#pragma unroll
      for (int r = 0; r < 16; ++r) {
        int rl = (r & 3) + 8 * (r >> 2) + 4 * lh;
        mrgb[(wb * 32 + rl) * 128 + cb * 32 + ln] = f2b(acc2[cb][r]);
      }
    if (l < 32) rs[wb * 32 + ln] = rsum;
  }
  __syncthreads();
  if (jh == 0) {
    unsigned short* hp;
    int rstr;
    if (blockIdx.y < 6) {
      hp = Hps + (size_t)blockIdx.y * ND;
      rstr = 128;
    } else {
      hp = Hx + (blockIdx.y - 6) * 128;
      rstr = 256;
    }
#pragma unroll
    for (int cb = 0; cb < 4; ++cb)
#pragma unroll
      for (int r = 0; r < 16; ++r) {
        int rl = (r & 3) + 8 * (r >> 2) + 4 * lh;
        float v = acc2[cb][r] + b2f(mrgb[(wb * 32 + rl) * 128 + cb * 32 + ln]);
        hp[(size_t)(i0 + wb * 32 + rl) * rstr + cb * 32 + ln] = f2b(v);
      }
    if (l < 32)
      rbp[(size_t)blockIdx.y * N + i0 + wb * 32 + ln] = rsum + rs[wb * 32 + ln];
  }
}

// ---------------------------------------------------------------------------
// Fused post-attention chain, 64 rows/block (R12/R13-exact, proven).
// ---------------------------------------------------------------------------
__device__ __forceinline__ void stageWf(const float* __restrict__ g,
                                        unsigned short (*L)[128], int t) {
#pragma unroll
  for (int idx = t; idx < 2048; idx += 512) {
    int r = idx >> 4, ch = idx & 15;
    const float* p = g + r * 128 + ch * 8;
    float4 u = *(const float4*)p, v = *(const float4*)(p + 4);
    bf16x8 o;
    o[0] = (short)f2b(u.x); o[1] = (short)f2b(u.y);
    o[2] = (short)f2b(u.z); o[3] = (short)f2b(u.w);
    o[4] = (short)f2b(v.x); o[5] = (short)f2b(v.y);
    o[6] = (short)f2b(v.z); o[7] = (short)f2b(v.w);
    *(bf16x8*)&L[r][(ch ^ (r & 15)) << 3] = o;
  }
}
__device__ __forceinline__ bf16x8 wfrag(const unsigned short (*L)[128], int row,
                                        int kc, int lh) {
  int ch = kc * 2 + lh;
  return *(const bf16x8*)&L[row][(ch ^ (row & 15)) << 3];
}

__global__ __launch_bounds__(512) void k_post(
    const unsigned short* __restrict__ Hps, const unsigned short* __restrict__ Hx,
    const float* __restrict__ rbp, const unsigned short* __restrict__ fselfb,
    const unsigned short* __restrict__ fbaseb,
    const float* __restrict__ Tf,
    const float* __restrict__ Wmf, const float* __restrict__ bm,
    const float* __restrict__ Wsf, const float* __restrict__ bs,
    const float* __restrict__ Wg1f, const float* __restrict__ bg1,
    const float* __restrict__ Wg2f, const float* __restrict__ bg2,
    float* __restrict__ outNorm, float* __restrict__ outValF,
    unsigned short* __restrict__ outValB, int N) {
  __shared__ unsigned short WL[128][128];
  __shared__ __align__(16) char pool[64 * 132 * 4];
  __shared__ float blds[3][128];
  __shared__ float rowpart[8][32];
  unsigned short(*Mb)[128] = (unsigned short(*)[128])pool;
  unsigned short(*Sb)[128] = (unsigned short(*)[128])(pool + 16384);
  float(*tr)[132] = (float(*)[132])pool;
  float(*hs)[132] = (float(*)[132])pool;

  const int t = threadIdx.x;
  const int w = t >> 6, l = t & 63, ln = l & 31, lh = l >> 5;
  const int grp = w >> 2, cq = w & 3;
  const int i0 = blockIdx.x * 64;
  const int lrow = grp * 32 + ln;
  const int row = i0 + lrow;
  const size_t ND = (size_t)N * DD;

  for (int idx = t; idx < 1024; idx += 512) {
    int r = idx >> 4, c8 = idx & 15;
    float a8[8] = {0.f, 0.f, 0.f, 0.f, 0.f, 0.f, 0.f, 0.f};
#pragma unroll
    for (int sp = 0; sp < 8; ++sp) {
      const unsigned short* p =
          (sp < 6) ? Hps + (size_t)sp * ND + (size_t)(i0 + r) * DD + c8 * 8
                   : Hx + (size_t)(i0 + r) * 256 + (sp - 6) * 128 + c8 * 8;
      bf16x8 v = *(const bf16x8*)p;
#pragma unroll
      for (int e = 0; e < 8; ++e) a8[e] += b2f((unsigned short)v[e]);
    }
    *(float4*)&hs[r][c8 * 8] = make_float4(a8[0], a8[1], a8[2], a8[3]);
    *(float4*)&hs[r][c8 * 8 + 4] = make_float4(a8[4], a8[5], a8[6], a8[7]);
  }
  if (t < 128) {
    blds[0][t] = bm[t];
    blds[1][t] = bs[t];
    blds[2][t] = bg1[t] + bg2[t];
  }
  stageWf(Tf, WL, t);
  __syncthreads();

  float rbv = 0.f;
#pragma unroll
  for (int sp = 0; sp < 8; ++sp) rbv += rbp[(size_t)sp * N + row];
  const float sc = (1.f / (float)N) / fmaxf(rbv, EPSN);
  bf16x8 bfA[8], bfS[8], bfB[8];
#pragma unroll
  for (int kc = 0; kc < 8; ++kc) {
    const float* hp = &hs[lrow][kc * 16 + lh * 8];
    float4 u = *(const float4*)hp;
    float4 v = *(const float4*)(hp + 4);
    bf16x8 a;
    a[0] = (short)f2b(u.x * sc); a[1] = (short)f2b(u.y * sc);
    a[2] = (short)f2b(u.z * sc); a[3] = (short)f2b(u.w * sc);
    a[4] = (short)f2b(v.x * sc); a[5] = (short)f2b(v.y * sc);
    a[6] = (short)f2b(v.z * sc); a[7] = (short)f2b(v.w * sc);
    bfA[kc] = a;
    bfS[kc] = *(const bf16x8*)(fselfb + (size_t)row * DD + kc * 16 + lh * 8);
    bfB[kc] = *(const bf16x8*)(fbaseb + (size_t)row * DD + kc * 16 + lh * 8);
  }

  f32x16 acc;
#pragma unroll
  for (int r = 0; r < 16; ++r) acc[r] = 0.f;
#pragma unroll
  for (int kc = 0; kc < 8; ++kc)
    acc = __builtin_amdgcn_mfma_f32_32x32x16_bf16(
        wfrag(WL, cq * 32 + ln, kc, lh), bfB[kc], acc, 0, 0, 0);
  float sab = 0.f;
#pragma unroll
  for (int r = 0; r < 16; ++r) sab += fabsf(acc[r]);
  sab += __shfl_xor(sab, 32);
  if (l < 32) rowpart[w][ln] = sab;
  __syncthreads();
  const float rsum = rowpart[grp * 4 + 0][ln] + rowpart[grp * 4 + 1][ln] +
                     rowpart[grp * 4 + 2][ln] + rowpart[grp * 4 + 3][ln];
  const float rinv = 1.f / fmaxf(rsum, EPSN);
  float basen[16];
#pragma unroll
  for (int r = 0; r < 16; ++r) basen[r] = acc[r] * rinv;

  __syncthreads();
  stageWf(Wmf, WL, t);
  __syncthreads();
#pragma unroll
  for (int r = 0; r < 16; ++r) acc[r] = 0.f;
#pragma unroll
  for (int kc = 0; kc < 8; ++kc)
    acc = __builtin_amdgcn_mfma_f32_32x32x16_bf16(
        wfrag(WL, cq * 32 + ln, kc, lh), bfA[kc], acc, 0, 0, 0);
#pragma unroll
  for (int r = 0; r < 16; ++r) {
    int c = cq * 32 + (r & 3) + 8 * (r >> 2) + 4 * lh;
    Mb[lrow][(((c >> 3) ^ (ln & 15)) << 3) + (c & 7)] = f2b(acc[r] + blds[0][c]);
  }
  __syncthreads();

  stageWf(Wsf, WL, t);
  __syncthreads();
#pragma unroll
  for (int r = 0; r < 16; ++r) acc[r] = 0.f;
#pragma unroll
  for (int kc = 0; kc < 8; ++kc)
    acc = __builtin_amdgcn_mfma_f32_32x32x16_bf16(
        wfrag(WL, cq * 32 + ln, kc, lh), bfS[kc], acc, 0, 0, 0);
#pragma unroll
  for (int r = 0; r < 16; ++r) {
    int c = cq * 32 + (r & 3) + 8 * (r >> 2) + 4 * lh;
    Sb[lrow][(((c >> 3) ^ (ln & 15)) << 3) + (c & 7)] = f2b(acc[r] + blds[1][c]);
  }
  __syncthreads();

  stageWf(Wg1f, WL, t);
  __syncthreads();
#pragma unroll
  for (int r = 0; r < 16; ++r) acc[r] = 0.f;
#pragma unroll
  for (int kc = 0; kc < 8; ++kc)
    acc = __builtin_amdgcn_mfma_f32_32x32x16_bf16(
        wfrag(WL, cq * 32 + ln, kc, lh), wfrag(Mb, lrow, kc, lh), acc, 0, 0, 0);
  __syncthreads();
  stageWf(Wg2f, WL, t);
  __syncthreads();
#pragma unroll
  for (int kc = 0; kc < 8; ++kc)
    acc = __builtin_amdgcn_mfma_f32_32x32x16_bf16(
        wfrag(WL, cq * 32 + ln, kc, lh), wfrag(Sb, lrow, kc, lh), acc, 0, 0, 0);

  float val[16];
#pragma unroll
  for (int r = 0; r < 16; ++r) {
    int c = cq * 32 + (r & 3) + 8 * (r >> 2) + 4 * lh;
    float z = acc[r] + blds[2][c];
    float g = 1.f / (1.f + __expf(-z));
    int off = (((c >> 3) ^ (ln & 15)) << 3) + (c & 7);
    float mv = b2f(Mb[lrow][off]);
    float sv = b2f(Sb[lrow][off]);
    val[r] = basen[r] + g * mv + (1.f - g) * sv;
  }

  const int orow = t >> 3, c0 = (t & 7) * 4;
  if (outNorm) {
    __syncthreads();
#pragma unroll
    for (int r = 0; r < 16; ++r)
      tr[lrow][cq * 32 + (r & 3) + 8 * (r >> 2) + 4 * lh] = basen[r];
    __syncthreads();
#pragma unroll
    for (int q = 0; q < 4; ++q)
      *(float4*)&outNorm[(size_t)(i0 + orow) * DD + c0 + 32 * q] =
          *(const float4*)&tr[orow][c0 + 32 * q];
  }
  __syncthreads();
#pragma unroll
  for (int r = 0; r < 16; ++r)
    tr[lrow][cq * 32 + (r & 3) + 8 * (r >> 2) + 4 * lh] = val[r];
  __syncthreads();
  if (outValF) {
#pragma unroll
    for (int q = 0; q < 4; ++q)
      *(float4*)&outValF[(size_t)(i0 + orow) * DD + c0 + 32 * q] =
          *(const float4*)&tr[orow][c0 + 32 * q];
  }
  if (outValB) {
#pragma unroll
    for (int q = 0; q < 4; ++q) {
      float4 v = *(const float4*)&tr[orow][c0 + 32 * q];
      ushort4 o;
      o.x = f2b(v.x); o.y = f2b(v.y); o.z = f2b(v.z); o.w = f2b(v.w);
      *(ushort4*)&outValB[(size_t)(i0 + orow) * DD + c0 + 32 * q] = o;
    }
  }
}

// ---------------------------------------------------------------------------
extern "C" void kernel_launch(void* const* d_in, const int* in_sizes, int n_in,
                              void* d_out, int out_size, void* d_ws,
                              size_t ws_size, hipStream_t stream) {
  const float* f1 = (const float*)d_in[0];
  const float* f2 = (const float*)d_in[1];
  const float* Wd1 = (const float*)d_in[2];
  const float* bd1 = (const float*)d_in[3];
  const float* Wd2 = (const float*)d_in[4];
  const float* bd2 = (const float*)d_in[5];
  const float* Ws1 = (const float*)d_in[6];
  const float* bs1 = (const float*)d_in[7];
  const float* Ws2 = (const float*)d_in[8];
  const float* bs2 = (const float*)d_in[9];
  const float* g1W1 = (const float*)d_in[10];
  const float* g1b1 = (const float*)d_in[11];
  const float* g1W2 = (const float*)d_in[12];
  const float* g1b2 = (const float*)d_in[13];
  const float* g2W1 = (const float*)d_in[14];
  const float* g2b1 = (const float*)d_in[15];
  const float* g2W2 = (const float*)d_in[16];
  const float* g2b2 = (const float*)d_in[17];

  const int N = in_sizes[0] / DD;  // 8192
  const size_t ND = (size_t)N * DD;

  float* ws = (float*)d_ws;
  float* T1 = ws;                                   // DD*DD f
  float* T2 = T1 + DD * DD;                         // DD*DD f
  float* rbp = T2 + DD * DD;                        // 8*N f
  unsigned short* f1bb = (unsigned short*)(rbp + 8 * (size_t)N);
  unsigned short* f2bb = f1bb + ND;
  unsigned short* f1nb = f2bb + ND;
  unsigned short* Hps = f1nb + ND;                  // 6*ND shorts (12MB)
  float* Tpart = (float*)Hps;                       // 128*DD*DD f (8MB, dead
                                                    // before attn writes Hps)
  float* out0 = (float*)d_out;
  float* out1 = out0 + ND;

  // Gram partials (atomic-free) + bf16 emission, then slice reduce
  k_ata_part<<<dim3(2, 2, 128), 256, 0, stream>>>(f1, f2, Tpart, f1bb, f2bb,
                                                  N / 64);
  k_tred<<<dim3(16, 2), 256, 0, stream>>>(Tpart, T1, T2);

  // --- message block 1: d2 -> d1 ---
  k_attn<<<dim3(N / 128, JSPLIT), 512, 0, stream>>>(
      f1bb, f2bb, Hps, (unsigned short*)out0, rbp, N);
  k_post<<<N / 64, 512, 0, stream>>>(Hps, (unsigned short*)out0, rbp, f2bb,
                                     f1bb, T1, Wd1, bd1, Ws1, bs1, g1W1, g1b1,
                                     g1W2, g1b2, out0, nullptr, f1nb, N);

  // --- message block 2: d1 -> d2 ---
  k_attn<<<dim3(N / 128, JSPLIT), 512, 0, stream>>>(
      f2bb, f1nb, Hps, (unsigned short*)out1, rbp, N);
  k_post<<<N / 64, 512, 0, stream>>>(Hps, (unsigned short*)out1, rbp, f1nb,
                                     f2bb, T2, Wd2, bd2, Ws2, bs2, g2W1, g2b1,
                                     g2W2, g2b2, nullptr, out1, nullptr, N);
}